// Round 1
// baseline (214.234 us; speedup 1.0000x reference)
//
#include <hip/hip_runtime.h>
#include <hip/hip_cooperative_groups.h>
#include <stdint.h>

namespace cg = cooperative_groups;

#define NPTS 512
#define NB 4
#define TJB 128
#define BST 72     // bS row stride (halfs): 144 B, 16B-aligned; b128 read patterns <=2-way
#define SOST 40    // sO row stride (halfs): 80 B, 16B-aligned half8 reads, <=2-way writes

typedef __attribute__((ext_vector_type(4))) float floatx4;
typedef __fp16 fp16x2 __attribute__((ext_vector_type(2)));      // cvt_pkrtz return type
typedef _Float16 half2v __attribute__((ext_vector_type(2)));
typedef _Float16 half8v __attribute__((ext_vector_type(8)));

union H8 { fp16x2 p2[4]; half2v h2[4]; half8v h8; };

// Shared memory overlay: row-phase scratch and pair-phase tiles never live together
// (grid.sync() separates them). Union keeps the block at 28,672 B -> 4 blocks/CU by LDS.
union SMem {
    struct { _Float16 bS[TJB][BST]; _Float16 sO[4][2][16][SOST]; } p;   // 28,672 B
    struct { float posh[2][64]; float red[2][2][64];
             float projS[2][64]; float embS[2][64]; } r;                //  2,560 B
};

// ---------------- Fused cooperative kernel ----------------
// Phase 1 (rows): 1024 blocks x 2 rows. Per row: 128 threads, t = output dim,
// kh = k-half. 64-long dots split across the two kh-waves (LDS reduce); the W1
// stage needs no reduce (kh0 -> A matrix, kh1 -> B matrix). vs the old 512-block
// layout: 2x waves/SIMD during rows, ~half the serial FMA chain.
// Phase 2 (pairs): identical to proven pairs_kernel; W2/W3/b2/b3 fragment loads
// hoisted BEFORE grid.sync so their latency hides under the barrier wait.
__global__ __launch_bounds__(256, 4) void fused_kernel(
    const float* __restrict__ x,
    const float* __restrict__ Wf,  const float* __restrict__ bf,
    const float* __restrict__ Wp1, const float* __restrict__ bp1,
    const float* __restrict__ Wp2, const float* __restrict__ bp2,
    const float* __restrict__ Wn,  const float* __restrict__ bn,
    const float* __restrict__ W1,  const float* __restrict__ b1,
    const float* __restrict__ W2,  const float* __restrict__ b2,
    const float* __restrict__ W3,  const float* __restrict__ b3,
    float* __restrict__ out,
    _Float16* __restrict__ wsA, _Float16* __restrict__ wsB)
{
    __shared__ SMem sm;
    const int tid = threadIdx.x;

    // ================= phase 1: per-row embedding chain =================
    {
        const int r2  = tid >> 7;          // row slot within block (0..1)
        const int kh  = (tid >> 6) & 1;    // k-half (0..1), wave-uniform
        const int t   = tid & 63;          // output dim
        const int row = blockIdx.x * 2 + r2;
        const float* xr = x + row * 16;
        const int k0 = kh << 5;

        // stage A: pos hidden = relu(xyz @ Wp1 + bp1)
        {
            const float x13 = xr[13], x14 = xr[14], x15 = xr[15];
            float ph = x13 * Wp1[t] + x14 * Wp1[64 + t] + x15 * Wp1[128 + t] + bp1[t];
            if (kh == 0) sm.r.posh[r2][t] = fmaxf(ph, 0.f);
        }
        __syncthreads();

        // stage B: half of (posh @ Wp2) + part of (feats @ Wf)
        {
            float s0 = 0.f, s1 = 0.f, s2 = 0.f, s3 = 0.f;
            #pragma unroll
            for (int k = 0; k < 32; k += 4) {
                s0 += sm.r.posh[r2][k0 + k    ] * Wp2[(k0 + k    ) * 64 + t];
                s1 += sm.r.posh[r2][k0 + k + 1] * Wp2[(k0 + k + 1) * 64 + t];
                s2 += sm.r.posh[r2][k0 + k + 2] * Wp2[(k0 + k + 2) * 64 + t];
                s3 += sm.r.posh[r2][k0 + k + 3] * Wp2[(k0 + k + 3) * 64 + t];
            }
            float part = (s0 + s1) + (s2 + s3);
            if (kh == 0) {
                #pragma unroll
                for (int k = 0; k < 6; ++k) part += xr[k] * Wf[k * 64 + t];
            } else {
                #pragma unroll
                for (int k = 6; k < 13; ++k) part += xr[k] * Wf[k * 64 + t];
            }
            sm.r.red[r2][kh][t] = part;
        }
        __syncthreads();
        if (kh == 0)
            sm.r.projS[r2][t] = sm.r.red[r2][0][t] + sm.r.red[r2][1][t] + bp2[t] + bf[t];
        __syncthreads();

        // stage C: half of (proj @ Wn)
        {
            float e0 = 0.f, e1 = 0.f, e2 = 0.f, e3 = 0.f;
            #pragma unroll
            for (int k = 0; k < 32; k += 4) {
                e0 += sm.r.projS[r2][k0 + k    ] * Wn[(k0 + k    ) * 64 + t];
                e1 += sm.r.projS[r2][k0 + k + 1] * Wn[(k0 + k + 1) * 64 + t];
                e2 += sm.r.projS[r2][k0 + k + 2] * Wn[(k0 + k + 2) * 64 + t];
                e3 += sm.r.projS[r2][k0 + k + 3] * Wn[(k0 + k + 3) * 64 + t];
            }
            sm.r.red[r2][kh][t] = (e0 + e1) + (e2 + e3);
        }
        __syncthreads();
        if (kh == 0)
            sm.r.embS[r2][t] = sm.r.red[r2][0][t] + sm.r.red[r2][1][t] + bn[t];
        __syncthreads();

        // stage D: kh0 -> a-row (b1 folded), kh1 -> b-row. Full 64-k dot each, no reduce.
        {
            const float* Wbase = W1 + (kh ? 64 * 64 : 0);
            float a0 = 0.f, a1 = 0.f, a2 = 0.f, a3 = 0.f;
            #pragma unroll
            for (int k = 0; k < 64; k += 4) {
                a0 += sm.r.embS[r2][k    ] * Wbase[(k    ) * 64 + t];
                a1 += sm.r.embS[r2][k + 1] * Wbase[(k + 1) * 64 + t];
                a2 += sm.r.embS[r2][k + 2] * Wbase[(k + 2) * 64 + t];
                a3 += sm.r.embS[r2][k + 3] * Wbase[(k + 3) * 64 + t];
            }
            const float resv = (a0 + a1) + (a2 + a3);
            if (kh == 0) wsA[row * 64 + t] = (_Float16)(resv + b1[t]);
            else         wsB[row * 64 + t] = (_Float16)resv;
        }
    }

    // ============ phase-2 setup (weights only — legal before grid sync) ============
    const int w   = tid >> 6;
    const int l   = tid & 63;
    const int q   = l >> 4;
    const int c   = l & 15;
    const int q8  = q * 8;

    const int bidx = blockIdx.x;
    const int jt = bidx & 3;             // 4 j-tiles of 128
    const int ig = (bidx >> 2) & 63;     // 64 i-groups of 8
    const int bb = bidx >> 8;            // batch
    const int j0 = jt * TJB;
    const int i0 = ig * 8 + w * 2;       // wave handles i0, i0+1

    // W2 f16 fragments, B-layout: lane holds W2[k=kt*32+q8+e][nt*16+c]
    half8v Wf16[2][2];
    #pragma unroll
    for (int kt = 0; kt < 2; ++kt)
        #pragma unroll
        for (int nt = 0; nt < 2; ++nt) {
            H8 u;
            #pragma unroll
            for (int e = 0; e < 8; ++e)
                u.h8[e] = (_Float16)W2[(kt * 32 + q8 + e) * 32 + nt * 16 + c];
            Wf16[kt][nt] = u.h8;
        }

    // W3 sigma-permuted B-frag: pos p holds W3[(p>>1)+16*(p&1)]
    half8v w3f;
    #pragma unroll
    for (int e = 0; e < 8; ++e) {
        const int p = q8 + e;
        w3f[e] = (_Float16)W3[(p >> 1) + ((p & 1) << 4)];
    }

    const float b2c = b2[c], b2c16 = b2[c + 16];
    const float b3v = b3[0];
    const half8v zero8 = (half8v)(_Float16)0.0f;

    // All wsA/wsB writes (all blocks, all XCDs) complete + visible past here.
    cg::this_grid().sync();

    // ================= phase 2: pairwise MLP =================
    // stage b-tile: 128 rows x 64 halfs = 16 KB
    const _Float16* bG = wsB + (bb * NPTS + j0) * 64;
    #pragma unroll
    for (int pgi = 0; pgi < 4; ++pgi) {
        const int flat = pgi * 256 + tid;
        const int rr = flat >> 3, ch = (flat & 7) * 8;
        *(half8v*)&sm.p.bS[rr][ch] = *(const half8v*)(bG + rr * 64 + ch);
    }

    // a-rows for both i (b1 folded), f16
    const _Float16* aG0 = wsA + (bb * NPTS + i0) * 64;
    const _Float16* aG1 = aG0 + 64;
    const half8v aA0 = *(const half8v*)(aG0 + q8);
    const half8v aA1 = *(const half8v*)(aG0 + 32 + q8);
    const half8v aB0 = *(const half8v*)(aG1 + q8);
    const half8v aB1 = *(const half8v*)(aG1 + 32 + q8);

    __syncthreads();

    float* orow0 = out + ((size_t)(bb * NPTS + i0)) * NPTS + j0;
    float* orow1 = orow0 + NPTS;

    #pragma unroll 2
    for (int mt = 0; mt < 8; ++mt) {
        const int m = mt * 16 + c;
        const half8v b0v = *(const half8v*)&sm.p.bS[m][q8];
        const half8v b1v = *(const half8v*)&sm.p.bS[m][32 + q8];

        // H = relu(a + b), packed f16; b-rows shared across both i
        const half8v hA0 = __builtin_elementwise_max(aA0 + b0v, zero8);
        const half8v hA1 = __builtin_elementwise_max(aA1 + b1v, zero8);
        const half8v hB0 = __builtin_elementwise_max(aB0 + b0v, zero8);
        const half8v hB1 = __builtin_elementwise_max(aB1 + b1v, zero8);

        floatx4 aA0c = {b2c, b2c, b2c, b2c};
        floatx4 aA1c = {b2c16, b2c16, b2c16, b2c16};
        floatx4 aB0c = aA0c, aB1c = aA1c;
        aA0c = __builtin_amdgcn_mfma_f32_16x16x32_f16(hA0, Wf16[0][0], aA0c, 0, 0, 0);
        aA0c = __builtin_amdgcn_mfma_f32_16x16x32_f16(hA1, Wf16[1][0], aA0c, 0, 0, 0);
        aA1c = __builtin_amdgcn_mfma_f32_16x16x32_f16(hA0, Wf16[0][1], aA1c, 0, 0, 0);
        aA1c = __builtin_amdgcn_mfma_f32_16x16x32_f16(hA1, Wf16[1][1], aA1c, 0, 0, 0);
        aB0c = __builtin_amdgcn_mfma_f32_16x16x32_f16(hB0, Wf16[0][0], aB0c, 0, 0, 0);
        aB0c = __builtin_amdgcn_mfma_f32_16x16x32_f16(hB1, Wf16[1][0], aB0c, 0, 0, 0);
        aB1c = __builtin_amdgcn_mfma_f32_16x16x32_f16(hB0, Wf16[0][1], aB1c, 0, 0, 0);
        aB1c = __builtin_amdgcn_mfma_f32_16x16x32_f16(hB1, Wf16[1][1], aB1c, 0, 0, 0);

        // epilogue, both i: R = relu(S) -> sigma position 2c -> LDS -> MFMA vs W3
        #pragma unroll
        for (int r = 0; r < 4; ++r) {
            H8 pkA, pkB;
            pkA.p2[0] = __builtin_amdgcn_cvt_pkrtz(aA0c[r], aA1c[r]);
            pkA.h2[0] = __builtin_elementwise_max(pkA.h2[0], (half2v)(_Float16)0.0f);
            *(half2v*)&sm.p.sO[w][0][q * 4 + r][2 * c] = pkA.h2[0];
            pkB.p2[0] = __builtin_amdgcn_cvt_pkrtz(aB0c[r], aB1c[r]);
            pkB.h2[0] = __builtin_elementwise_max(pkB.h2[0], (half2v)(_Float16)0.0f);
            *(half2v*)&sm.p.sO[w][1][q * 4 + r][2 * c] = pkB.h2[0];
        }
        const half8v arA = *(const half8v*)&sm.p.sO[w][0][c][q8];
        const half8v arB = *(const half8v*)&sm.p.sO[w][1][c][q8];

        floatx4 dlA = {b3v, b3v, b3v, b3v};
        floatx4 dlB = {b3v, b3v, b3v, b3v};
        dlA = __builtin_amdgcn_mfma_f32_16x16x32_f16(arA, w3f, dlA, 0, 0, 0);
        dlB = __builtin_amdgcn_mfma_f32_16x16x32_f16(arB, w3f, dlB, 0, 0, 0);

        const float lgA = (c == 0) ? dlA[0] : ((c == 1) ? dlA[1] : ((c == 2) ? dlA[2] : dlA[3]));
        const float lgB = (c == 0) ? dlB[0] : ((c == 1) ? dlB[1] : ((c == 2) ? dlB[2] : dlB[3]));
        if (c < 4) {
            orow0[mt * 16 + q * 4 + c] = lgA;
            orow1[mt * 16 + q * 4 + c] = lgB;
        }
    }
}

// ---------------- Fallback kernels (proven 96.8 us path) ----------------
__global__ __launch_bounds__(256) void rows_kernel(
    const float* __restrict__ x,
    const float* __restrict__ Wf,  const float* __restrict__ bf,
    const float* __restrict__ Wp1, const float* __restrict__ bp1,
    const float* __restrict__ Wp2, const float* __restrict__ bp2,
    const float* __restrict__ Wn,  const float* __restrict__ bn,
    const float* __restrict__ W1,  const float* __restrict__ b1,
    _Float16* __restrict__ wsA, _Float16* __restrict__ wsB)
{
    __shared__ float posh[4][64];
    __shared__ float projS[4][64];
    __shared__ float embS[4][64];

    const int r   = threadIdx.x >> 6;
    const int t   = threadIdx.x & 63;
    const int row = blockIdx.x * 4 + r;
    const float* xr = x + row * 16;

    const float x13 = xr[13], x14 = xr[14], x15 = xr[15];
    float ph = x13 * Wp1[t] + x14 * Wp1[64 + t] + x15 * Wp1[128 + t] + bp1[t];
    posh[r][t] = fmaxf(ph, 0.f);
    __syncthreads();

    float s0 = 0.f, s1 = 0.f, s2 = 0.f, s3 = 0.f;
    #pragma unroll
    for (int k = 0; k < 64; k += 4) {
        s0 += posh[r][k    ] * Wp2[(k    ) * 64 + t];
        s1 += posh[r][k + 1] * Wp2[(k + 1) * 64 + t];
        s2 += posh[r][k + 2] * Wp2[(k + 2) * 64 + t];
        s3 += posh[r][k + 3] * Wp2[(k + 3) * 64 + t];
    }
    float acc = bp2[t] + ((s0 + s1) + (s2 + s3)) + bf[t];
    float f0 = 0.f, f1 = 0.f, f2 = 0.f, f3 = 0.f;
    #pragma unroll
    for (int k = 0; k < 12; k += 4) {
        f0 += xr[k    ] * Wf[(k    ) * 64 + t];
        f1 += xr[k + 1] * Wf[(k + 1) * 64 + t];
        f2 += xr[k + 2] * Wf[(k + 2) * 64 + t];
        f3 += xr[k + 3] * Wf[(k + 3) * 64 + t];
    }
    acc += ((f0 + f1) + (f2 + f3)) + xr[12] * Wf[12 * 64 + t];
    projS[r][t] = acc;
    __syncthreads();

    float e0 = 0.f, e1 = 0.f, e2 = 0.f, e3 = 0.f;
    #pragma unroll
    for (int k = 0; k < 64; k += 4) {
        e0 += projS[r][k    ] * Wn[(k    ) * 64 + t];
        e1 += projS[r][k + 1] * Wn[(k + 1) * 64 + t];
        e2 += projS[r][k + 2] * Wn[(k + 2) * 64 + t];
        e3 += projS[r][k + 3] * Wn[(k + 3) * 64 + t];
    }
    embS[r][t] = bn[t] + ((e0 + e1) + (e2 + e3));
    __syncthreads();

    float a0 = 0.f, a1 = 0.f, a2 = 0.f, a3 = 0.f;
    float v0 = 0.f, v1 = 0.f, v2 = 0.f, v3 = 0.f;
    #pragma unroll
    for (int k = 0; k < 64; k += 4) {
        const float g0 = embS[r][k], g1 = embS[r][k + 1], g2 = embS[r][k + 2], g3 = embS[r][k + 3];
        a0 += g0 * W1[(k    ) * 64 + t];
        a1 += g1 * W1[(k + 1) * 64 + t];
        a2 += g2 * W1[(k + 2) * 64 + t];
        a3 += g3 * W1[(k + 3) * 64 + t];
        v0 += g0 * W1[(64 + k    ) * 64 + t];
        v1 += g1 * W1[(64 + k + 1) * 64 + t];
        v2 += g2 * W1[(64 + k + 2) * 64 + t];
        v3 += g3 * W1[(64 + k + 3) * 64 + t];
    }
    wsA[row * 64 + t] = (_Float16)(b1[t] + ((a0 + a1) + (a2 + a3)));
    wsB[row * 64 + t] = (_Float16)((v0 + v1) + (v2 + v3));
}

__global__ __launch_bounds__(256) void pairs_kernel(
    const _Float16* __restrict__ wsA, const _Float16* __restrict__ wsB,
    const float* __restrict__ W2,  const float* __restrict__ b2,
    const float* __restrict__ W3,  const float* __restrict__ b3,
    float* __restrict__ out)
{
    __shared__ _Float16 bS[TJB][BST];
    __shared__ _Float16 sO[4][2][16][SOST];

    const int tid = threadIdx.x;
    const int w   = tid >> 6;
    const int l   = tid & 63;
    const int q   = l >> 4;
    const int c   = l & 15;
    const int q8  = q * 8;

    const int bidx = blockIdx.x;
    const int jt = bidx & 3;
    const int ig = (bidx >> 2) & 63;
    const int bb = bidx >> 8;
    const int j0 = jt * TJB;
    const int i0 = ig * 8 + w * 2;

    const _Float16* bG = wsB + (bb * NPTS + j0) * 64;
    #pragma unroll
    for (int p = 0; p < 4; ++p) {
        const int flat = p * 256 + tid;
        const int rr = flat >> 3, ch = (flat & 7) * 8;
        *(half8v*)&bS[rr][ch] = *(const half8v*)(bG + rr * 64 + ch);
    }

    half8v Wf16[2][2];
    #pragma unroll
    for (int kt = 0; kt < 2; ++kt)
        #pragma unroll
        for (int nt = 0; nt < 2; ++nt) {
            H8 u;
            #pragma unroll
            for (int e = 0; e < 8; ++e)
                u.h8[e] = (_Float16)W2[(kt * 32 + q8 + e) * 32 + nt * 16 + c];
            Wf16[kt][nt] = u.h8;
        }

    half8v w3f;
    #pragma unroll
    for (int e = 0; e < 8; ++e) {
        const int p = q8 + e;
        w3f[e] = (_Float16)W3[(p >> 1) + ((p & 1) << 4)];
    }

    const float b2c = b2[c], b2c16 = b2[c + 16];
    const float b3v = b3[0];

    const _Float16* aG0 = wsA + (bb * NPTS + i0) * 64;
    const _Float16* aG1 = aG0 + 64;
    const half8v aA0 = *(const half8v*)(aG0 + q8);
    const half8v aA1 = *(const half8v*)(aG0 + 32 + q8);
    const half8v aB0 = *(const half8v*)(aG1 + q8);
    const half8v aB1 = *(const half8v*)(aG1 + 32 + q8);
    const half8v zero8 = (half8v)(_Float16)0.0f;

    __syncthreads();

    float* orow0 = out + ((size_t)(bb * NPTS + i0)) * NPTS + j0;
    float* orow1 = orow0 + NPTS;

    #pragma unroll 2
    for (int mt = 0; mt < 8; ++mt) {
        const int m = mt * 16 + c;
        const half8v b0v = *(const half8v*)&bS[m][q8];
        const half8v b1v = *(const half8v*)&bS[m][32 + q8];

        const half8v hA0 = __builtin_elementwise_max(aA0 + b0v, zero8);
        const half8v hA1 = __builtin_elementwise_max(aA1 + b1v, zero8);
        const half8v hB0 = __builtin_elementwise_max(aB0 + b0v, zero8);
        const half8v hB1 = __builtin_elementwise_max(aB1 + b1v, zero8);

        floatx4 aA0c = {b2c, b2c, b2c, b2c};
        floatx4 aA1c = {b2c16, b2c16, b2c16, b2c16};
        floatx4 aB0c = aA0c, aB1c = aA1c;
        aA0c = __builtin_amdgcn_mfma_f32_16x16x32_f16(hA0, Wf16[0][0], aA0c, 0, 0, 0);
        aA0c = __builtin_amdgcn_mfma_f32_16x16x32_f16(hA1, Wf16[1][0], aA0c, 0, 0, 0);
        aA1c = __builtin_amdgcn_mfma_f32_16x16x32_f16(hA0, Wf16[0][1], aA1c, 0, 0, 0);
        aA1c = __builtin_amdgcn_mfma_f32_16x16x32_f16(hA1, Wf16[1][1], aA1c, 0, 0, 0);
        aB0c = __builtin_amdgcn_mfma_f32_16x16x32_f16(hB0, Wf16[0][0], aB0c, 0, 0, 0);
        aB0c = __builtin_amdgcn_mfma_f32_16x16x32_f16(hB1, Wf16[1][0], aB0c, 0, 0, 0);
        aB1c = __builtin_amdgcn_mfma_f32_16x16x32_f16(hB0, Wf16[0][1], aB1c, 0, 0, 0);
        aB1c = __builtin_amdgcn_mfma_f32_16x16x32_f16(hB1, Wf16[1][1], aB1c, 0, 0, 0);

        #pragma unroll
        for (int r = 0; r < 4; ++r) {
            H8 pkA, pkB;
            pkA.p2[0] = __builtin_amdgcn_cvt_pkrtz(aA0c[r], aA1c[r]);
            pkA.h2[0] = __builtin_elementwise_max(pkA.h2[0], (half2v)(_Float16)0.0f);
            *(half2v*)&sO[w][0][q * 4 + r][2 * c] = pkA.h2[0];
            pkB.p2[0] = __builtin_amdgcn_cvt_pkrtz(aB0c[r], aB1c[r]);
            pkB.h2[0] = __builtin_elementwise_max(pkB.h2[0], (half2v)(_Float16)0.0f);
            *(half2v*)&sO[w][1][q * 4 + r][2 * c] = pkB.h2[0];
        }
        const half8v arA = *(const half8v*)&sO[w][0][c][q8];
        const half8v arB = *(const half8v*)&sO[w][1][c][q8];

        floatx4 dlA = {b3v, b3v, b3v, b3v};
        floatx4 dlB = {b3v, b3v, b3v, b3v};
        dlA = __builtin_amdgcn_mfma_f32_16x16x32_f16(arA, w3f, dlA, 0, 0, 0);
        dlB = __builtin_amdgcn_mfma_f32_16x16x32_f16(arB, w3f, dlB, 0, 0, 0);

        const float lgA = (c == 0) ? dlA[0] : ((c == 1) ? dlA[1] : ((c == 2) ? dlA[2] : dlA[3]));
        const float lgB = (c == 0) ? dlB[0] : ((c == 1) ? dlB[1] : ((c == 2) ? dlB[2] : dlB[3]));
        if (c < 4) {
            orow0[mt * 16 + q * 4 + c] = lgA;
            orow1[mt * 16 + q * 4 + c] = lgB;
        }
    }
}

extern "C" void kernel_launch(void* const* d_in, const int* in_sizes, int n_in,
                              void* d_out, int out_size, void* d_ws, size_t ws_size,
                              hipStream_t stream) {
    const float* x   = (const float*)d_in[0];
    const float* Wf  = (const float*)d_in[1];
    const float* bf  = (const float*)d_in[2];
    const float* Wp1 = (const float*)d_in[3];
    const float* bp1 = (const float*)d_in[4];
    const float* Wp2 = (const float*)d_in[5];
    const float* bp2 = (const float*)d_in[6];
    const float* Wn  = (const float*)d_in[7];
    const float* bn  = (const float*)d_in[8];
    const float* W1  = (const float*)d_in[9];
    const float* b1  = (const float*)d_in[10];
    const float* W2  = (const float*)d_in[11];
    const float* b2  = (const float*)d_in[12];
    const float* W3  = (const float*)d_in[13];
    const float* b3  = (const float*)d_in[14];

    _Float16* wsA = (_Float16*)d_ws;           // 2048*64 halfs (256 KB)
    _Float16* wsB = wsA + NB * NPTS * 64;      // 2048*64 halfs
    float* outp   = (float*)d_out;

    // Single cooperative dispatch: 1024 blocks x 256 thr = exactly 4 blocks/CU
    // (LDS 28.7 KB -> 5/CU; __launch_bounds__(256,4) -> VGPR<=128 -> 4 waves/SIMD).
    void* args[] = { (void*)&x, (void*)&Wf, (void*)&bf, (void*)&Wp1, (void*)&bp1,
                     (void*)&Wp2, (void*)&bp2, (void*)&Wn, (void*)&bn,
                     (void*)&W1, (void*)&b1, (void*)&W2, (void*)&b2,
                     (void*)&W3, (void*)&b3, (void*)&outp, (void*)&wsA, (void*)&wsB };
    hipError_t err = hipLaunchCooperativeKernel((void*)fused_kernel,
                                                dim3(NB * 64 * 4), dim3(256),
                                                args, 0, stream);
    if (err != hipSuccess) {
        // Fallback: proven two-kernel path.
        rows_kernel<<<NB * NPTS / 4, 256, 0, stream>>>(
            x, Wf, bf, Wp1, bp1, Wp2, bp2, Wn, bn, W1, b1, wsA, wsB);
        pairs_kernel<<<NB * 64 * 4, 256, 0, stream>>>(
            wsA, wsB, W2, b2, W3, b3, (float*)d_out);
    }
}

// Round 2
// 97.803 us; speedup vs baseline: 2.1905x; 2.1905x over previous
//
#include <hip/hip_runtime.h>
#include <stdint.h>

#define NPTS 512
#define NB 4
#define TJB 128
#define BST 72     // bS row stride (halfs): 144 B, 16B-aligned; b128 read patterns <=2-way
#define SOST 40    // sO row stride (halfs): 80 B, 16B-aligned half8 reads, <=2-way writes

typedef __attribute__((ext_vector_type(4))) float floatx4;
typedef __fp16 fp16x2 __attribute__((ext_vector_type(2)));      // cvt_pkrtz return type
typedef _Float16 half2v __attribute__((ext_vector_type(2)));
typedef _Float16 half8v __attribute__((ext_vector_type(8)));

union H8 { fp16x2 p2[4]; half2v h2[4]; half8v h8; };

// ---------------- Kernel 1: per-row embedding chain ----------------
__global__ __launch_bounds__(256) void rows_kernel(
    const float* __restrict__ x,
    const float* __restrict__ Wf,  const float* __restrict__ bf,
    const float* __restrict__ Wp1, const float* __restrict__ bp1,
    const float* __restrict__ Wp2, const float* __restrict__ bp2,
    const float* __restrict__ Wn,  const float* __restrict__ bn,
    const float* __restrict__ W1,  const float* __restrict__ b1,
    _Float16* __restrict__ wsA, _Float16* __restrict__ wsB)
{
    __shared__ float posh[4][64];
    __shared__ float projS[4][64];
    __shared__ float embS[4][64];

    const int r   = threadIdx.x >> 6;
    const int t   = threadIdx.x & 63;
    const int row = blockIdx.x * 4 + r;
    const float* xr = x + row * 16;

    const float x13 = xr[13], x14 = xr[14], x15 = xr[15];
    float ph = x13 * Wp1[t] + x14 * Wp1[64 + t] + x15 * Wp1[128 + t] + bp1[t];
    posh[r][t] = fmaxf(ph, 0.f);
    __syncthreads();

    float s0 = 0.f, s1 = 0.f, s2 = 0.f, s3 = 0.f;
    #pragma unroll
    for (int k = 0; k < 64; k += 4) {
        s0 += posh[r][k    ] * Wp2[(k    ) * 64 + t];
        s1 += posh[r][k + 1] * Wp2[(k + 1) * 64 + t];
        s2 += posh[r][k + 2] * Wp2[(k + 2) * 64 + t];
        s3 += posh[r][k + 3] * Wp2[(k + 3) * 64 + t];
    }
    float acc = bp2[t] + ((s0 + s1) + (s2 + s3)) + bf[t];
    float f0 = 0.f, f1 = 0.f, f2 = 0.f, f3 = 0.f;
    #pragma unroll
    for (int k = 0; k < 12; k += 4) {
        f0 += xr[k    ] * Wf[(k    ) * 64 + t];
        f1 += xr[k + 1] * Wf[(k + 1) * 64 + t];
        f2 += xr[k + 2] * Wf[(k + 2) * 64 + t];
        f3 += xr[k + 3] * Wf[(k + 3) * 64 + t];
    }
    acc += ((f0 + f1) + (f2 + f3)) + xr[12] * Wf[12 * 64 + t];
    projS[r][t] = acc;
    __syncthreads();

    float e0 = 0.f, e1 = 0.f, e2 = 0.f, e3 = 0.f;
    #pragma unroll
    for (int k = 0; k < 64; k += 4) {
        e0 += projS[r][k    ] * Wn[(k    ) * 64 + t];
        e1 += projS[r][k + 1] * Wn[(k + 1) * 64 + t];
        e2 += projS[r][k + 2] * Wn[(k + 2) * 64 + t];
        e3 += projS[r][k + 3] * Wn[(k + 3) * 64 + t];
    }
    embS[r][t] = bn[t] + ((e0 + e1) + (e2 + e3));
    __syncthreads();

    float a0 = 0.f, a1 = 0.f, a2 = 0.f, a3 = 0.f;
    float v0 = 0.f, v1 = 0.f, v2 = 0.f, v3 = 0.f;
    #pragma unroll
    for (int k = 0; k < 64; k += 4) {
        const float g0 = embS[r][k], g1 = embS[r][k + 1], g2 = embS[r][k + 2], g3 = embS[r][k + 3];
        a0 += g0 * W1[(k    ) * 64 + t];
        a1 += g1 * W1[(k + 1) * 64 + t];
        a2 += g2 * W1[(k + 2) * 64 + t];
        a3 += g3 * W1[(k + 3) * 64 + t];
        v0 += g0 * W1[(64 + k    ) * 64 + t];
        v1 += g1 * W1[(64 + k + 1) * 64 + t];
        v2 += g2 * W1[(64 + k + 2) * 64 + t];
        v3 += g3 * W1[(64 + k + 3) * 64 + t];
    }
    wsA[row * 64 + t] = (_Float16)(b1[t] + ((a0 + a1) + (a2 + a3)));  // b1 folded
    wsB[row * 64 + t] = (_Float16)((v0 + v1) + (v2 + v3));
}

// ---------------- Kernel 2: pairwise MLP, packed-f16 MFMA, 2 i/wave ----------------
// Block: 4 waves x 2 i = 8 i x 128 j. Per mt (16 j): shared b-row reads feed both
// i-chains; 8 main MFMA + 2 epilogue MFMA; independent chains give ILP across the
// epilogue's LDS round-trip.
__global__ __launch_bounds__(256) void pairs_kernel(
    const _Float16* __restrict__ wsA, const _Float16* __restrict__ wsB,
    const float* __restrict__ W2,  const float* __restrict__ b2,
    const float* __restrict__ W3,  const float* __restrict__ b3,
    float* __restrict__ out)
{
    __shared__ _Float16 bS[TJB][BST];
    __shared__ _Float16 sO[4][2][16][SOST];   // [wave][i-slot][j][sigma-m]

    const int tid = threadIdx.x;
    const int w   = tid >> 6;
    const int l   = tid & 63;
    const int q   = l >> 4;
    const int c   = l & 15;
    const int q8  = q * 8;

    const int bidx = blockIdx.x;
    const int jt = bidx & 3;             // 4 j-tiles of 128
    const int ig = (bidx >> 2) & 63;     // 64 i-groups of 8
    const int bb = bidx >> 8;            // batch
    const int j0 = jt * TJB;
    const int i0 = ig * 8 + w * 2;       // wave handles i0, i0+1

    // stage b-tile: 128 rows x 64 halfs = 16 KB
    const _Float16* bG = wsB + (bb * NPTS + j0) * 64;
    #pragma unroll
    for (int p = 0; p < 4; ++p) {
        const int flat = p * 256 + tid;
        const int rr = flat >> 3, ch = (flat & 7) * 8;
        *(half8v*)&bS[rr][ch] = *(const half8v*)(bG + rr * 64 + ch);
    }

    // W2 f16 fragments, B-layout: lane holds W2[k=kt*32+q8+e][nt*16+c]
    half8v Wf16[2][2];
    #pragma unroll
    for (int kt = 0; kt < 2; ++kt)
        #pragma unroll
        for (int nt = 0; nt < 2; ++nt) {
            H8 u;
            #pragma unroll
            for (int e = 0; e < 8; ++e)
                u.h8[e] = (_Float16)W2[(kt * 32 + q8 + e) * 32 + nt * 16 + c];
            Wf16[kt][nt] = u.h8;
        }

    // W3 sigma-permuted B-frag: pos p holds W3[(p>>1)+16*(p&1)]
    half8v w3f;
    #pragma unroll
    for (int e = 0; e < 8; ++e) {
        const int p = q8 + e;
        w3f[e] = (_Float16)W3[(p >> 1) + ((p & 1) << 4)];
    }

    const float b2c = b2[c], b2c16 = b2[c + 16];
    const float b3v = b3[0];

    // a-rows for both i (b1 folded), f16
    const _Float16* aG0 = wsA + (bb * NPTS + i0) * 64;
    const _Float16* aG1 = aG0 + 64;
    const half8v aA0 = *(const half8v*)(aG0 + q8);
    const half8v aA1 = *(const half8v*)(aG0 + 32 + q8);
    const half8v aB0 = *(const half8v*)(aG1 + q8);
    const half8v aB1 = *(const half8v*)(aG1 + 32 + q8);
    const half8v zero8 = (half8v)(_Float16)0.0f;

    __syncthreads();

    float* orow0 = out + ((size_t)(bb * NPTS + i0)) * NPTS + j0;
    float* orow1 = orow0 + NPTS;

    #pragma unroll 2
    for (int mt = 0; mt < 8; ++mt) {
        const int m = mt * 16 + c;
        const half8v b0v = *(const half8v*)&bS[m][q8];
        const half8v b1v = *(const half8v*)&bS[m][32 + q8];

        // H = relu(a + b), packed f16; b-rows shared across both i
        const half8v hA0 = __builtin_elementwise_max(aA0 + b0v, zero8);
        const half8v hA1 = __builtin_elementwise_max(aA1 + b1v, zero8);
        const half8v hB0 = __builtin_elementwise_max(aB0 + b0v, zero8);
        const half8v hB1 = __builtin_elementwise_max(aB1 + b1v, zero8);

        floatx4 aA0c = {b2c, b2c, b2c, b2c};
        floatx4 aA1c = {b2c16, b2c16, b2c16, b2c16};
        floatx4 aB0c = aA0c, aB1c = aA1c;
        aA0c = __builtin_amdgcn_mfma_f32_16x16x32_f16(hA0, Wf16[0][0], aA0c, 0, 0, 0);
        aA0c = __builtin_amdgcn_mfma_f32_16x16x32_f16(hA1, Wf16[1][0], aA0c, 0, 0, 0);
        aA1c = __builtin_amdgcn_mfma_f32_16x16x32_f16(hA0, Wf16[0][1], aA1c, 0, 0, 0);
        aA1c = __builtin_amdgcn_mfma_f32_16x16x32_f16(hA1, Wf16[1][1], aA1c, 0, 0, 0);
        aB0c = __builtin_amdgcn_mfma_f32_16x16x32_f16(hB0, Wf16[0][0], aB0c, 0, 0, 0);
        aB0c = __builtin_amdgcn_mfma_f32_16x16x32_f16(hB1, Wf16[1][0], aB0c, 0, 0, 0);
        aB1c = __builtin_amdgcn_mfma_f32_16x16x32_f16(hB0, Wf16[0][1], aB1c, 0, 0, 0);
        aB1c = __builtin_amdgcn_mfma_f32_16x16x32_f16(hB1, Wf16[1][1], aB1c, 0, 0, 0);

        // epilogue, both i: R = relu(S) -> sigma position 2c -> LDS -> MFMA vs W3
        #pragma unroll
        for (int r = 0; r < 4; ++r) {
            H8 pkA, pkB;
            pkA.p2[0] = __builtin_amdgcn_cvt_pkrtz(aA0c[r], aA1c[r]);
            pkA.h2[0] = __builtin_elementwise_max(pkA.h2[0], (half2v)(_Float16)0.0f);
            *(half2v*)&sO[w][0][q * 4 + r][2 * c] = pkA.h2[0];
            pkB.p2[0] = __builtin_amdgcn_cvt_pkrtz(aB0c[r], aB1c[r]);
            pkB.h2[0] = __builtin_elementwise_max(pkB.h2[0], (half2v)(_Float16)0.0f);
            *(half2v*)&sO[w][1][q * 4 + r][2 * c] = pkB.h2[0];
        }
        const half8v arA = *(const half8v*)&sO[w][0][c][q8];
        const half8v arB = *(const half8v*)&sO[w][1][c][q8];

        floatx4 dlA = {b3v, b3v, b3v, b3v};
        floatx4 dlB = {b3v, b3v, b3v, b3v};
        dlA = __builtin_amdgcn_mfma_f32_16x16x32_f16(arA, w3f, dlA, 0, 0, 0);
        dlB = __builtin_amdgcn_mfma_f32_16x16x32_f16(arB, w3f, dlB, 0, 0, 0);

        const float lgA = (c == 0) ? dlA[0] : ((c == 1) ? dlA[1] : ((c == 2) ? dlA[2] : dlA[3]));
        const float lgB = (c == 0) ? dlB[0] : ((c == 1) ? dlB[1] : ((c == 2) ? dlB[2] : dlB[3]));
        if (c < 4) {
            orow0[mt * 16 + q * 4 + c] = lgA;
            orow1[mt * 16 + q * 4 + c] = lgB;
        }
    }
}

extern "C" void kernel_launch(void* const* d_in, const int* in_sizes, int n_in,
                              void* d_out, int out_size, void* d_ws, size_t ws_size,
                              hipStream_t stream) {
    const float* x   = (const float*)d_in[0];
    const float* Wf  = (const float*)d_in[1];
    const float* bf  = (const float*)d_in[2];
    const float* Wp1 = (const float*)d_in[3];
    const float* bp1 = (const float*)d_in[4];
    const float* Wp2 = (const float*)d_in[5];
    const float* bp2 = (const float*)d_in[6];
    const float* Wn  = (const float*)d_in[7];
    const float* bn  = (const float*)d_in[8];
    const float* W1  = (const float*)d_in[9];
    const float* b1  = (const float*)d_in[10];
    const float* W2  = (const float*)d_in[11];
    const float* b2  = (const float*)d_in[12];
    const float* W3  = (const float*)d_in[13];
    const float* b3  = (const float*)d_in[14];

    _Float16* wsA = (_Float16*)d_ws;           // 2048*64 halfs (256 KB)
    _Float16* wsB = wsA + NB * NPTS * 64;      // 2048*64 halfs

    rows_kernel<<<NB * NPTS / 4, 256, 0, stream>>>(
        x, Wf, bf, Wp1, bp1, Wp2, bp2, Wn, bn, W1, b1, wsA, wsB);

    pairs_kernel<<<NB * 64 * 4, 256, 0, stream>>>(
        wsA, wsB, W2, b2, W3, b3, (float*)d_out);
}